// Round 1
// baseline (302.665 us; speedup 1.0000x reference)
//
#include <hip/hip_runtime.h>

constexpr int B  = 8,  P = 50, N = 128, M = 128;
constexpr int EMB = 128, H = 8, D = 16;
constexpr int NE = 8;
constexpr int HD = H * D;        // 128
constexpr int E1 = EMB + 1;      // 129
constexpr int BP = B * P;        // 400
constexpr int T  = BP * N;       // 51200 tokens

// ---------------------------------------------------------------------------
// K0: We'[e][f] = sum_o We[e][f][o]*Wfinal[o]; b'[e] = be[e].Wfinal.
// ---------------------------------------------------------------------------
__global__ void prep_kernel(const float* __restrict__ We,
                            const float* __restrict__ be,
                            const float* __restrict__ Wf,
                            float* __restrict__ Wep, float* __restrict__ bpv,
                            float* __restrict__ importance) {
    const int e = blockIdx.x;
    const int f = threadIdx.x;

    float a = 0.f;
    const long base = ((long)e * HD + f) * E1;
    for (int o = 0; o < E1; ++o) a += We[base + o] * Wf[o];
    Wep[e * HD + f] = a;

    if (f == 0) {
        float b = 0.f;
        for (int o = 0; o < E1; ++o) b += be[(long)e * E1 + o] * Wf[o];
        bpv[e] = b;
    }
    if (e == 0 && f < NE) importance[f] = 0.f;
}

// ---------------------------------------------------------------------------
// K1: q/k/v projections (r7-proven). grid (400, 3), block 256. 128x128 tile,
// 8x8 acc, K-tile 8, ping-pong LDS, one barrier per tile, reg-staged loads.
// ---------------------------------------------------------------------------
__global__ __launch_bounds__(256) void proj_kernel(
    const float* __restrict__ nodes,  // [T][128]
    const float* __restrict__ routes, // [T][129]
    const float* __restrict__ Wq, const float* __restrict__ Wk,
    const float* __restrict__ Wv,
    float* __restrict__ qo, float* __restrict__ ko, float* __restrict__ vo) {
    const int mat = blockIdx.y;
    const float* __restrict__ X = (mat == 0) ? nodes : routes;
    const float* __restrict__ W = (mat == 0) ? Wq : (mat == 1 ? Wk : Wv);
    float* __restrict__ out     = (mat == 0) ? qo : (mat == 1 ? ko : vo);
    const int Kd = (mat == 0) ? EMB : E1;
    const int nit = (Kd + 7) >> 3;

    const int row0 = blockIdx.x * 128;
    const int tid  = threadIdx.x;
    const int tr   = tid >> 4;        // 0..15
    const int tc   = tid & 15;        // 0..15

    __shared__ float XT[2][8][132];   // [buf][k][row], padded
    __shared__ float WS[2][8][132];   // [buf][k][col]

    float acc[8][8];
    #pragma unroll
    for (int i = 0; i < 8; ++i)
        #pragma unroll
        for (int j = 0; j < 8; ++j) acc[i][j] = 0.f;

    float xr[4];
    float4 wr;
    const int xkx = tid & 7, xrr = tid >> 3;          // +i*32 rows
    const int wkx = tid >> 5, wc4 = (tid & 31) * 4;

    {   // prologue: fetch tile 0
        #pragma unroll
        for (int i = 0; i < 4; ++i) {
            int kg = xkx;
            xr[i] = (kg < Kd) ? X[(long)(row0 + xrr + i * 32) * Kd + kg] : 0.f;
        }
        wr = (wkx < Kd) ? *(const float4*)&W[(long)wkx * HD + wc4]
                        : make_float4(0.f, 0.f, 0.f, 0.f);
        #pragma unroll
        for (int i = 0; i < 4; ++i) XT[0][xkx][xrr + i * 32] = xr[i];
        *(float4*)&WS[0][wkx][wc4] = wr;
    }
    __syncthreads();

    for (int it = 0; it < nit; ++it) {
        const int buf = it & 1;
        if (it + 1 < nit) {
            const int kk = (it + 1) * 8;
            #pragma unroll
            for (int i = 0; i < 4; ++i) {
                int kg = kk + xkx;
                xr[i] = (kg < Kd) ? X[(long)(row0 + xrr + i * 32) * Kd + kg] : 0.f;
            }
            int kg = kk + wkx;
            wr = (kg < Kd) ? *(const float4*)&W[(long)kg * HD + wc4]
                           : make_float4(0.f, 0.f, 0.f, 0.f);
        }

        #pragma unroll
        for (int k = 0; k < 8; ++k) {
            float4 xa = *(const float4*)&XT[buf][k][tr * 4];
            float4 xb = *(const float4*)&XT[buf][k][64 + tr * 4];
            float4 wa = *(const float4*)&WS[buf][k][tc * 4];
            float4 wb = *(const float4*)&WS[buf][k][64 + tc * 4];
            float xv[8] = {xa.x, xa.y, xa.z, xa.w, xb.x, xb.y, xb.z, xb.w};
            float wvv[8] = {wa.x, wa.y, wa.z, wa.w, wb.x, wb.y, wb.z, wb.w};
            #pragma unroll
            for (int i = 0; i < 8; ++i)
                #pragma unroll
                for (int j = 0; j < 8; ++j) acc[i][j] += xv[i] * wvv[j];
        }

        if (it + 1 < nit) {
            const int nb = buf ^ 1;
            #pragma unroll
            for (int i = 0; i < 4; ++i) XT[nb][xkx][xrr + i * 32] = xr[i];
            *(float4*)&WS[nb][wkx][wc4] = wr;
        }
        __syncthreads();
    }

    #pragma unroll
    for (int i = 0; i < 8; ++i) {
        int r = row0 + (i < 4 ? 0 : 64) + tr * 4 + (i & 3);
        float4 o0 = make_float4(acc[i][0], acc[i][1], acc[i][2], acc[i][3]);
        float4 o1 = make_float4(acc[i][4], acc[i][5], acc[i][6], acc[i][7]);
        *(float4*)&out[(long)r * HD + tc * 4]      = o0;
        *(float4*)&out[(long)r * HD + 64 + tc * 4] = o1;
    }
}

// ---------------------------------------------------------------------------
// K2: masked attention per (bp, head). grid (BP, 8), block 128 (2 waves).
// r12 restructure: 1 query row per thread (was 2), k AND v staged in LDS
// (16 KB/block -> 10 blocks/CU LDS cap = 20 waves/CU, vs 1-wave blocks'
// 12.5 waves/CU launch cap). Doubles resident waves (3200->6400) and
// halves each thread's serial FMA chain -> latency-bound fix.
// Dot product uses 4 partial accumulators to shorten the dependence chain.
// ---------------------------------------------------------------------------
__global__ __launch_bounds__(128) void attn_kernel(
    const float* __restrict__ qbuf,   // [T][128]
    const float* __restrict__ kbuf,   // [T][128]
    const float* __restrict__ vbuf,   // [T][128]
    const float* __restrict__ rmask,  // [BP*N][M]
    const float* __restrict__ ninf,   // [BP*N]
    float* __restrict__ xcat) {       // [T][128]
    const int bp  = blockIdx.x;
    const int h   = blockIdx.y;
    const int tid = threadIdx.x;      // 0..127 = query row

    __shared__ float kh[M][D];        // 8 KB
    __shared__ float vh[M][D];        // 8 KB

    // stage k and v head slices: 512 float4 each, 128 threads -> 4 iters
    #pragma unroll
    for (int i = 0; i < 4; ++i) {
        int e = tid + i * 128;        // f4 index 0..511
        int r = e >> 2, c4 = (e & 3) * 4;
        const long src = ((long)bp * M + r) * HD + h * D + c4;
        *(float4*)&kh[r][c4] = *(const float4*)&kbuf[src];
        *(float4*)&vh[r][c4] = *(const float4*)&vbuf[src];
    }
    __syncthreads();

    const long t = (long)bp * N + tid;

    // q row, 1/sqrt(D)=0.25 folded in
    float qr[16];
    {
        const float4* q0 = (const float4*)&qbuf[t * HD + h * D];
        #pragma unroll
        for (int i = 0; i < 4; ++i) {
            float4 a = q0[i];
            qr[i*4+0] = a.x*0.25f; qr[i*4+1] = a.y*0.25f;
            qr[i*4+2] = a.z*0.25f; qr[i*4+3] = a.w*0.25f;
        }
    }

    const float4* rm = (const float4*)&rmask[t * M];

    float sum = 0.f;
    float o[16];
    #pragma unroll
    for (int d = 0; d < 16; ++d) o[d] = 0.f;

    for (int mb = 0; mb < 32; ++mb) {          // NOT force-unrolled (VGPR!)
        float4 r4 = rm[mb];
        float rv[4] = {r4.x, r4.y, r4.z, r4.w};
        #pragma unroll
        for (int j = 0; j < 4; ++j) {
            const int m = mb * 4 + j;
            const float4* k4 = (const float4*)&kh[m][0];  // uniform -> LDS broadcast
            // 4 partial sums: dependence chain 4 FMAs deep instead of 16
            float sA = 0.f, sB = 0.f, sC = 0.f, sD = 0.f;
            {
                float4 k0 = k4[0], k1 = k4[1], k2 = k4[2], k3 = k4[3];
                sA = qr[0]*k0.x + qr[1]*k0.y + qr[2]*k0.z + qr[3]*k0.w;
                sB = qr[4]*k1.x + qr[5]*k1.y + qr[6]*k1.z + qr[7]*k1.w;
                sC = qr[8]*k2.x + qr[9]*k2.y + qr[10]*k2.z + qr[11]*k2.w;
                sD = qr[12]*k3.x + qr[13]*k3.y + qr[14]*k3.z + qr[15]*k3.w;
            }
            float s = (sA + sB) + (sC + sD);
            float e = __expf(s + rv[j]);
            sum += e;
            const float4* v4 = (const float4*)&vh[m][0];  // uniform -> LDS broadcast
            #pragma unroll
            for (int q4 = 0; q4 < 4; ++q4) {
                float4 vq = v4[q4];
                o[q4*4+0] += e*vq.x; o[q4*4+1] += e*vq.y;
                o[q4*4+2] += e*vq.z; o[q4*4+3] += e*vq.w;
            }
        }
    }

    const float inv = ((ninf[t] == 0.f) ? 1.f : 0.f) / sum;
    #pragma unroll
    for (int q4 = 0; q4 < 4; ++q4) {
        float4 w = make_float4(o[q4*4+0]*inv, o[q4*4+1]*inv,
                               o[q4*4+2]*inv, o[q4*4+3]*inv);
        *(float4*)&xcat[t * HD + h * D + q4 * 4] = w;
    }
}

// ---------------------------------------------------------------------------
// K3: MoE gating (top-2) + collapsed expert scoring + final softmax.
// grid BP, block 128 (thread = token n). (r5/r7-proven version)
// ---------------------------------------------------------------------------
__global__ __launch_bounds__(128) void moe_final_kernel(
    const float* __restrict__ xcat, const float* __restrict__ Wg,
    const float* __restrict__ ninf, const float* __restrict__ Wep,
    const float* __restrict__ bpv, float* __restrict__ importance,
    float* __restrict__ out) {
    __shared__ float WgS[EMB][NE];   // 4 KB
    __shared__ float WeS[NE][132];   // padded
    __shared__ float red[N];
    __shared__ float impS[NE];

    const int bp = blockIdx.x;
    const int n  = threadIdx.x;

    #pragma unroll
    for (int i = 0; i < 2; ++i) {
        int e = n + i * 128;
        int r = e >> 1, c4 = (e & 1) * 4;
        *(float4*)&WgS[r][c4] = *(const float4*)&Wg[(long)r * NE + c4];
    }
    #pragma unroll
    for (int i = 0; i < 2; ++i) {
        int idx = n + i * 128;
        int r = idx >> 5, c = (idx & 31) * 4;
        *(float4*)&WeS[r][c] = *(const float4*)&Wep[(long)r * HD + c];
    }
    if (n < NE) impS[n] = 0.f;
    __syncthreads();

    const long t = (long)bp * N + n;
    const float4* row4 = (const float4*)&xcat[t * HD];

    float gl[NE];
    #pragma unroll
    for (int e = 0; e < NE; ++e) gl[e] = 0.f;
    for (int fb = 0; fb < 32; ++fb) {
        float4 xv = row4[fb];
        float x4[4] = {xv.x, xv.y, xv.z, xv.w};
        #pragma unroll
        for (int j = 0; j < 4; ++j)
            #pragma unroll
            for (int e = 0; e < NE; ++e) gl[e] += x4[j] * WgS[fb * 4 + j][e];
    }

    int e0 = 0; float v0 = gl[0];
    #pragma unroll
    for (int e = 1; e < NE; ++e) if (gl[e] > v0) { v0 = gl[e]; e0 = e; }
    int e1 = -1; float v1 = -3.4e38f;
    #pragma unroll
    for (int e = 0; e < NE; ++e) if (e != e0 && gl[e] > v1) { v1 = gl[e]; e1 = e; }
    float ex = __expf(v1 - v0);
    float g0 = 1.f / (1.f + ex);
    float g1 = ex / (1.f + ex);

    atomicAdd(&impS[e0], g0);
    atomicAdd(&impS[e1], g1);

    float s = g0 * bpv[e0] + g1 * bpv[e1];
    for (int fb = 0; fb < 32; ++fb) {
        float4 xv = row4[fb];
        float x4[4] = {xv.x, xv.y, xv.z, xv.w};
        #pragma unroll
        for (int j = 0; j < 4; ++j) {
            int f = fb * 4 + j;
            s += x4[j] * (g0 * WeS[e0][f] + g1 * WeS[e1][f]);
        }
    }
    s = 10.f * tanhf(s) + ninf[t];

    red[n] = s;
    __syncthreads();
    for (int off = 64; off > 0; off >>= 1) {
        if (n < off) red[n] = fmaxf(red[n], red[n + off]);
        __syncthreads();
    }
    float mx = red[0];
    __syncthreads();
    float e = __expf(s - mx);
    red[n] = e;
    __syncthreads();
    for (int off = 64; off > 0; off >>= 1) {
        if (n < off) red[n] += red[n + off];
        __syncthreads();
    }
    float sum = red[0];

    out[t] = e / sum;

    if (n < NE) atomicAdd(&importance[n], impS[n]);
}

// ---------------------------------------------------------------------------
// K4: moe_loss from importance (f32 at out[T]).
// ---------------------------------------------------------------------------
__global__ void loss_kernel(const float* __restrict__ importance,
                            float* __restrict__ out) {
    if (threadIdx.x == 0) {
        float mean = 0.f;
        #pragma unroll
        for (int e = 0; e < NE; ++e) mean += importance[e];
        mean *= (1.f / NE);
        float var = 0.f;
        #pragma unroll
        for (int e = 0; e < NE; ++e) {
            float d = importance[e] - mean;
            var += d * d;
        }
        var *= (1.f / NE);
        out[T] = var / (mean * mean + 1e-10f);
    }
}

// ---------------------------------------------------------------------------
extern "C" void kernel_launch(void* const* d_in, const int* in_sizes, int n_in,
                              void* d_out, int out_size, void* d_ws, size_t ws_size,
                              hipStream_t stream) {
    const float* nodes  = (const float*)d_in[0];
    const float* routes = (const float*)d_in[1];
    const float* ninf   = (const float*)d_in[2];
    const float* rmask  = (const float*)d_in[3];
    const float* Wq     = (const float*)d_in[4];
    const float* Wk     = (const float*)d_in[5];
    const float* Wv     = (const float*)d_in[6];
    const float* Wg     = (const float*)d_in[7];
    const float* We     = (const float*)d_in[8];
    const float* be     = (const float*)d_in[9];
    const float* Wfin   = (const float*)d_in[10];

    float* ws = (float*)d_ws;
    float* Wep        = ws + 16;
    float* bpv        = ws + 1040;
    float* importance = ws + 1048;
    float* qbuf       = ws + 4096;
    float* kbuf       = qbuf + (long)T * HD;
    float* vbuf       = kbuf + (long)T * HD;
    float* xcat       = vbuf + (long)T * HD;

    float* out = (float*)d_out;

    prep_kernel<<<NE, 128, 0, stream>>>(We, be, Wfin, Wep, bpv, importance);
    proj_kernel<<<dim3(400, 3), 256, 0, stream>>>(nodes, routes, Wq, Wk, Wv,
                                                  qbuf, kbuf, vbuf);
    attn_kernel<<<dim3(BP, H), 128, 0, stream>>>(qbuf, kbuf, vbuf,
                                                 rmask, ninf, xcat);
    moe_final_kernel<<<BP, 128, 0, stream>>>(xcat, Wg, ninf, Wep, bpv,
                                             importance, out);
    loss_kernel<<<1, 64, 0, stream>>>(importance, out);
}